// Round 3
// baseline (572.248 us; speedup 1.0000x reference)
//
#include <hip/hip_runtime.h>
#include <hip/hip_bf16.h>

typedef __attribute__((ext_vector_type(8))) short short8;   // 8 bf16 (4 VGPRs)
typedef __attribute__((ext_vector_type(4))) float f32x4;    // MFMA acc

#define NH   4
#define NB   1024
#define NL   200
#define NDQ  512
#define NDF  128
#define ND1  128
#define ND2  64
#define KP   128            // k-stride (bf16 elems) -> 256B rows (global, no banks)
#define NW   13             // active warps = M-tiles (13*16 = 208 >= 200 rows)
#define NT   (NW*64)        // 832 threads

// workspace layout (bytes)
#define OFF_WQC   0                                    // fp32 [H][512][64]   524288
#define OFF_BQC   (NH*NDQ*ND2*4)                       // fp32 [H][64]
#define OFF_FQ    (OFF_BQC + NH*ND2*4)                 // fp32 [H][B][64]
#define OFF_WIMG  (OFF_FQ + NH*NB*ND2*4)               // bf16 [H][3][64][KP] (slots: Wf_hi, Wf_lo, Wv_hi)
#define OFF_BFC   (OFF_WIMG + NH*3*ND2*KP*2)           // fp32 [H][64]
#define OFF_BVC   (OFF_BFC + NH*ND2*4)                 // fp32 [H][64]

__device__ inline short f2bf(float f) {                // RN-even fp32 -> bf16 bits
    union { float f; unsigned u; } v; v.f = f;
    unsigned r = (v.u + 0x7FFFu + ((v.u >> 16) & 1u)) >> 16;
    return (short)r;
}
__device__ inline float bf2f(short s) {
    union { unsigned u; float f; } v; v.u = ((unsigned)(unsigned short)s) << 16;
    return v.f;
}
__device__ inline float fsilu(float z) {               // fast silu
    return z * __fdividef(1.f, 1.f + __expf(-z));
}

// ---------------- K1: fuse weights (identity between FC layers) ----------------
__global__ __launch_bounds__(256) void k_combine(
    const float* __restrict__ Wq1, const float* __restrict__ bq1,
    const float* __restrict__ Wq2, const float* __restrict__ bq2,
    const float* __restrict__ Wf1, const float* __restrict__ bf1,
    const float* __restrict__ Wf2, const float* __restrict__ bf2,
    const float* __restrict__ Wv1, const float* __restrict__ bv1,
    const float* __restrict__ Wv2, const float* __restrict__ bv2,
    float* __restrict__ WQC, float* __restrict__ BQC,
    __hip_bfloat16* __restrict__ WIMG, float* __restrict__ BFC, float* __restrict__ BVC)
{
    int g = blockIdx.x * 256 + threadIdx.x;
    if (g < NH*NDQ*ND2) {                       // Wqc = Wq1@Wq2 (fp32 exact)
        int h = g >> 15, r = g & 32767, i = r >> 6, j = r & 63;
        const float* a  = Wq1 + (h*NDQ + i)*ND1;
        const float* bb = Wq2 + h*ND1*ND2 + j;
        float s = 0.f;
        for (int k = 0; k < ND1; ++k) s += a[k] * bb[k*ND2];
        WQC[(h*NDQ + i)*ND2 + j] = s;
        return;
    }
    g -= NH*NDQ*ND2;
    if (g < 2*NH*NDF*ND2) {                     // Wfc (hi+lo) / Wvc (hi), transposed image
        int which = (g >= NH*NDF*ND2);
        int r0 = g & (NH*NDF*ND2 - 1);
        int h = r0 >> 13, r = r0 & 8191, i = r >> 6, j = r & 63;
        const float* W1 = (which ? Wv1 : Wf1) + (h*NDF + i)*ND1;
        const float* W2 = (which ? Wv2 : Wf2) + h*ND1*ND2 + j;
        float s = 0.f;
        for (int k = 0; k < ND1; ++k) s += W1[k] * W2[k*ND2];
        short hi = f2bf(s);
        short lo = f2bf(s - bf2f(hi));
        __hip_bfloat16* img = WIMG + (size_t)((h*3 + (which ? 2 : 0))*ND2 + j)*KP + i; // [col=j][k=i]
        ((short*)img)[0] = hi;
        if (!which) ((short*)img)[ND2*KP] = lo;  // Wf lo slot
        return;
    }
    g -= 2*NH*NDF*ND2;
    if (g < NH*ND2) {                           // bqc = bq1@Wq2 + bq2
        int h = g >> 6, j = g & 63;
        float s = bq2[h*ND2 + j];
        for (int k = 0; k < ND1; ++k) s += bq1[h*ND1 + k] * Wq2[(h*ND1 + k)*ND2 + j];
        BQC[g] = s; return;
    }
    g -= NH*ND2;
    if (g < NH*ND2) {
        int h = g >> 6, j = g & 63;
        float s = bf2[h*ND2 + j];
        for (int k = 0; k < ND1; ++k) s += bf1[h*ND1 + k] * Wf2[(h*ND1 + k)*ND2 + j];
        BFC[g] = s; return;
    }
    g -= NH*ND2;
    if (g < NH*ND2) {
        int h = g >> 6, j = g & 63;
        float s = bv2[h*ND2 + j];
        for (int k = 0; k < ND1; ++k) s += bv1[h*ND1 + k] * Wv2[(h*ND1 + k)*ND2 + j];
        BVC[g] = s; return;
    }
}

// ---------------- K2: fq = silu(q @ Wqc + bqc) ----------------
__global__ __launch_bounds__(256) void k_fq(
    const float* __restrict__ query, const float* __restrict__ WQC,
    const float* __restrict__ BQC, float* __restrict__ FQ)
{
    __shared__ __align__(16) float qS[2*NDQ];
    const int t = threadIdx.x;
    const int b0 = blockIdx.x * 2;
    {
        const float4* src = (const float4*)(query + (size_t)b0 * NDQ);
        ((float4*)qS)[t] = src[t];              // 256 float4 = 2 x 512 floats
    }
    __syncthreads();
    const int h = t >> 6, d = t & 63;
    float s0, s1;
    s0 = s1 = BQC[h*ND2 + d];
    const float* wp = WQC + (size_t)h*NDQ*ND2 + d;
    #pragma unroll 16
    for (int i = 0; i < NDQ; ++i) {
        float wv = wp[i*ND2];
        s0 += qS[i]       * wv;
        s1 += qS[NDQ + i] * wv;
    }
    float* o = FQ + ((size_t)h*NB + b0)*ND2 + d;
    o[0]   = fsilu(s0);
    o[ND2] = fsilu(s1);
}

// ---------------- K3: main fused attention ----------------
// Grid = 4096 blocks, one (b,h) pair each; 832 threads (13 warps), one M-tile
// per warp. NO LDS weight staging: B-fragments are read straight from the
// 196 KB L2-resident weight image -> no staging barriers, no lockstep, LDS
// is just the 7 KB merge buffer. ONE barrier per block (before the LSE
// merge). XCD-aware block swizzle keeps each b's 4 head-blocks on one XCD
// so fact[b] is fetched into that XCD's L2 once.
__global__ __launch_bounds__(NT) void k_main(
    const float* __restrict__ fact,
    const int* __restrict__ mask,
    const float* __restrict__ mmc,
    const float* __restrict__ tau1,
    const float* __restrict__ tau2,
    const float* __restrict__ FQ,
    const float* __restrict__ BFC,
    const float* __restrict__ BVC,
    const __hip_bfloat16* __restrict__ WIMG,
    float* __restrict__ out)
{
    __shared__ __align__(16) float pS[NW][132];             // per warp: m, s, oE[64], oS[64]

    const int t    = threadIdx.x;
    const int blk  = blockIdx.x;
    // XCD swizzle: XCD x (= blk%8) gets b in [x*128, (x+1)*128), h-inner.
    const int x    = blk & 7;
    const int i0   = blk >> 3;                  // 0..511
    const int b    = x * (NB/8) + (i0 >> 2);
    const int h    = i0 & 3;
    const int w    = t >> 6;                    // 0..12 = M-tile index
    const int lane = t & 63;
    const int a15  = lane & 15;
    const int quad = lane >> 4;

    const int bL = b * NL;

    // A fragments: this warp's 16 fact rows, hi/lo bf16.
    short8 afh[4], afl[4];
    const short8 zero8 = {0,0,0,0,0,0,0,0};
    {
        int row = w*16 + a15;
        for (int kk = 0; kk < 4; ++kk) {
            short8 vh = zero8, vl = zero8;
            if (row < NL) {
                const float* p = fact + ((size_t)(bL + row))*NDF + kk*32 + quad*8;
                float4 x0 = *(const float4*)p;
                float4 x1 = *(const float4*)(p + 4);
                float v[8] = {x0.x, x0.y, x0.z, x0.w, x1.x, x1.y, x1.z, x1.w};
                for (int j = 0; j < 8; ++j) {
                    short hs = f2bf(v[j]);
                    vh[j] = hs;
                    vl[j] = f2bf(v[j] - bf2f(hs));
                }
            }
            afh[kk] = vh;
            afl[kk] = vl;
        }
    }

    // head-invariant per-row data (mask penalty + cosine terms)
    float mkv[4], c0v[4], c1v[4];
    {
        int rbase = w*16 + quad*4;
        for (int rg = 0; rg < 4; ++rg) {
            int r = rbase + rg;
            if (r < NL) {
                mkv[rg] = 1e9f * (1.0f - (float)mask[bL + r]);
                c0v[rg] = mmc[bL + r];
                c1v[rg] = mmc[NB*NL + bL + r];
            } else { mkv[rg] = 0.f; c0v[rg] = 0.f; c1v[rg] = 0.f; }
        }
    }

    const float rt1a = __fdividef(1.f, tau1[h]);
    const float rt1b = __fdividef(1.f, tau1[NH + h]);
    const float t20 = tau2[h];
    const float t21 = tau2[NH + h];
    const float t22 = tau2[2*NH + h];

    float fqv[4], bfcv[4];
    for (int nt = 0; nt < 4; ++nt) {
        int col = nt*16 + a15;
        fqv[nt]  = FQ[((size_t)h*NB + b)*ND2 + col];
        bfcv[nt] = BFC[h*ND2 + col];
    }

    const f32x4 zf = {0.f, 0.f, 0.f, 0.f};
    const __hip_bfloat16* Wh = WIMG + (size_t)(h*3)*ND2*KP;

    // ---- ff GEMM, 3 passes: f_hi*w_hi + f_hi*w_lo + f_lo*w_hi (B from L2) ----
    f32x4 acc[4];
    for (int nt = 0; nt < 4; ++nt) acc[nt] = zf;
    __builtin_amdgcn_s_setprio(1);
    for (int kk = 0; kk < 4; ++kk) {
        short8 bh[4], bl[4];
        for (int nt = 0; nt < 4; ++nt) {
            const __hip_bfloat16* p = Wh + (nt*16 + a15)*KP + kk*32 + quad*8;
            bh[nt] = *(const short8*)p;
            bl[nt] = *(const short8*)(p + ND2*KP);
        }
        for (int nt = 0; nt < 4; ++nt) {
            acc[nt] = __builtin_amdgcn_mfma_f32_16x16x32_bf16(afh[kk], bh[nt], acc[nt], 0, 0, 0);
            acc[nt] = __builtin_amdgcn_mfma_f32_16x16x32_bf16(afh[kk], bl[nt], acc[nt], 0, 0, 0);
            acc[nt] = __builtin_amdgcn_mfma_f32_16x16x32_bf16(afl[kk], bh[nt], acc[nt], 0, 0, 0);
        }
    }
    __builtin_amdgcn_s_setprio(0);

    // ---- epilogue: silu, dot with fq (butterfly -> row-dot in all 16 lanes
    //      of each quad-group), mask + cosine bias -> logits ----
    float lg[4];
    for (int rg = 0; rg < 4; ++rg) {
        float l = -3.0e38f;
        float s = 0.f;
        for (int nt = 0; nt < 4; ++nt)
            s += fsilu(acc[nt][rg] + bfcv[nt]) * fqv[nt];
        s += __shfl_xor(s, 1);
        s += __shfl_xor(s, 2);
        s += __shfl_xor(s, 4);
        s += __shfl_xor(s, 8);
        int r = w*16 + quad*4 + rg;
        if (r < NL) {
            float dv = s - mkv[rg];
            float bias = c0v[rg]*rt1a + c1v[rg]*rt1b;
            l = t20*dv + t21*bias + t22*dv*bias;
        }
        lg[rg] = l;
    }

    // ---- warp-local softmax over own 16 rows ----
    float m = fmaxf(fmaxf(lg[0], lg[1]), fmaxf(lg[2], lg[3]));
    m = fmaxf(m, __shfl_xor(m, 16));
    m = fmaxf(m, __shfl_xor(m, 32));
    float sw = 0.f;
    for (int rg = 0; rg < 4; ++rg) {
        float p = __expf(lg[rg] - m);           // invalid rows underflow to 0
        lg[rg] = p;
        sw += p;
    }
    sw += __shfl_xor(sw, 16);
    sw += __shfl_xor(sw, 32);

    // ---- fv GEMM: single hi*hi pass (slot 2), reuse acc ----
    for (int nt = 0; nt < 4; ++nt) acc[nt] = zf;
    __builtin_amdgcn_s_setprio(1);
    for (int kk = 0; kk < 4; ++kk) {
        short8 bv[4];
        for (int nt = 0; nt < 4; ++nt)
            bv[nt] = *(const short8*)(Wh + (2*ND2 + nt*16 + a15)*KP + kk*32 + quad*8);
        for (int nt = 0; nt < 4; ++nt)
            acc[nt] = __builtin_amdgcn_mfma_f32_16x16x32_bf16(afh[kk], bv[nt], acc[nt], 0, 0, 0);
    }
    __builtin_amdgcn_s_setprio(0);

    // ---- AV: oE = sum p*silu(fv), oS = sum silu(fv) (for the +1e-7 term) ----
    float bvcv[4];
    for (int nt = 0; nt < 4; ++nt) bvcv[nt] = BVC[h*ND2 + nt*16 + a15];
    float oE[4] = {0.f,0.f,0.f,0.f}, oS[4] = {0.f,0.f,0.f,0.f};
    for (int rg = 0; rg < 4; ++rg) {
        float p = lg[rg];
        int r = w*16 + quad*4 + rg;
        float vm = (r < NL) ? 1.f : 0.f;
        for (int nt = 0; nt < 4; ++nt) {
            float sv = fsilu(acc[nt][rg] + bvcv[nt]);
            oE[nt] += p * sv;
            oS[nt] += vm * sv;
        }
    }
    for (int nt = 0; nt < 4; ++nt) {
        oE[nt] += __shfl_xor(oE[nt], 16);
        oE[nt] += __shfl_xor(oE[nt], 32);
        oS[nt] += __shfl_xor(oS[nt], 16);
        oS[nt] += __shfl_xor(oS[nt], 32);
    }
    if (lane == 0) { pS[w][0] = m; pS[w][1] = sw; }
    if (quad == 0)
        for (int nt = 0; nt < 4; ++nt) {
            pS[w][2  + nt*16 + a15] = oE[nt];
            pS[w][66 + nt*16 + a15] = oS[nt];
        }
    __syncthreads();                            // the ONLY barrier

    // LSE-merge of 13 warps, write output for this head
    if (t < 64) {
        float M = pS[0][0];
        for (int ww = 1; ww < NW; ++ww) M = fmaxf(M, pS[ww][0]);
        float den = 0.f, num = 0.f, s1 = 0.f;
        for (int ww = 0; ww < NW; ++ww) {
            float e = __expf(pS[ww][0] - M);
            den += e * pS[ww][1];
            num += e * pS[ww][2 + t];
            s1  += pS[ww][66 + t];
        }
        out[(size_t)b*(NH*ND2) + h*ND2 + t] = num * __fdividef(1.f, den) + 1e-7f * s1;
    }
}

extern "C" void kernel_launch(void* const* d_in, const int* in_sizes, int n_in,
                              void* d_out, int out_size, void* d_ws, size_t ws_size,
                              hipStream_t stream) {
    const float* query = (const float*)d_in[0];
    const float* fact  = (const float*)d_in[1];
    const int*   maskp = (const int*)d_in[2];
    const float* mmc   = (const float*)d_in[3];
    const float* Wq1 = (const float*)d_in[4];
    const float* bq1 = (const float*)d_in[5];
    const float* Wq2 = (const float*)d_in[6];
    const float* bq2 = (const float*)d_in[7];
    const float* Wf1 = (const float*)d_in[8];
    const float* bf1 = (const float*)d_in[9];
    const float* Wf2 = (const float*)d_in[10];
    const float* bf2 = (const float*)d_in[11];
    const float* Wv1 = (const float*)d_in[12];
    const float* bv1 = (const float*)d_in[13];
    const float* Wv2 = (const float*)d_in[14];
    const float* bv2 = (const float*)d_in[15];
    const float* tau1 = (const float*)d_in[16];
    const float* tau2 = (const float*)d_in[17];

    char* ws = (char*)d_ws;
    float*          WQC  = (float*)(ws + OFF_WQC);
    float*          BQC  = (float*)(ws + OFF_BQC);
    float*          FQ   = (float*)(ws + OFF_FQ);
    __hip_bfloat16* WIMG = (__hip_bfloat16*)(ws + OFF_WIMG);
    float*          BFC  = (float*)(ws + OFF_BFC);
    float*          BVC  = (float*)(ws + OFF_BVC);

    k_combine<<<771, 256, 0, stream>>>(Wq1, bq1, Wq2, bq2, Wf1, bf1, Wf2, bf2,
                                       Wv1, bv1, Wv2, bv2, WQC, BQC, WIMG, BFC, BVC);
    k_fq<<<NB/2, 256, 0, stream>>>(query, WQC, BQC, FQ);
    k_main<<<NB*NH, NT, 0, stream>>>(fact, maskp, mmc, tau1, tau2, FQ, BFC, BVC, WIMG,
                                     (float*)d_out);
}

// Round 5
// 361.588 us; speedup vs baseline: 1.5826x; 1.5826x over previous
//
#include <hip/hip_runtime.h>
#include <hip/hip_bf16.h>

typedef __attribute__((ext_vector_type(8))) short short8;   // 8 bf16 (4 VGPRs)
typedef __attribute__((ext_vector_type(4))) float f32x4;    // MFMA acc

#define NH   4
#define NB   1024
#define NL   200
#define NDQ  512
#define NDF  128
#define ND1  128
#define ND2  64
#define KP   128            // k-stride (bf16 elems); conflicts handled by rotation swizzle
#define NW   13             // active warps = M-tiles (13*16 = 208 >= 200 rows)
#define NT   (NW*64)        // 832 threads
#define SGRAN (3*ND2*16)    // 3072 float4 granules per head image

// workspace layout (bytes)
#define OFF_WQC   0                                    // fp32 [H][512][64]   524288
#define OFF_BQC   (NH*NDQ*ND2*4)                       // fp32 [H][64]
#define OFF_FQ    (OFF_BQC + NH*ND2*4)                 // fp32 [H][B][64]
#define OFF_WIMG  (OFF_FQ + NH*NB*ND2*4)               // bf16 [H][3][64][KP] (slots: Wf_hi, Wf_lo, Wv_hi)
#define OFF_BFC   (OFF_WIMG + NH*3*ND2*KP*2)           // fp32 [H][64]
#define OFF_BVC   (OFF_BFC + NH*ND2*4)                 // fp32 [H][64]

__device__ inline short f2bf(float f) {                // RN-even fp32 -> bf16 bits
    union { float f; unsigned u; } v; v.f = f;
    unsigned r = (v.u + 0x7FFFu + ((v.u >> 16) & 1u)) >> 16;
    return (short)r;
}
__device__ inline float bf2f(short s) {
    union { unsigned u; float f; } v; v.u = ((unsigned)(unsigned short)s) << 16;
    return v.f;
}
__device__ inline float fsilu(float z) {               // fast silu
    return z * __fdividef(1.f, 1.f + __expf(-z));
}

// ---------------- K1: fuse weights (identity between FC layers) ----------------
__global__ __launch_bounds__(256) void k_combine(
    const float* __restrict__ Wq1, const float* __restrict__ bq1,
    const float* __restrict__ Wq2, const float* __restrict__ bq2,
    const float* __restrict__ Wf1, const float* __restrict__ bf1,
    const float* __restrict__ Wf2, const float* __restrict__ bf2,
    const float* __restrict__ Wv1, const float* __restrict__ bv1,
    const float* __restrict__ Wv2, const float* __restrict__ bv2,
    float* __restrict__ WQC, float* __restrict__ BQC,
    __hip_bfloat16* __restrict__ WIMG, float* __restrict__ BFC, float* __restrict__ BVC)
{
    int g = blockIdx.x * 256 + threadIdx.x;
    if (g < NH*NDQ*ND2) {                       // Wqc = Wq1@Wq2 (fp32 exact)
        int h = g >> 15, r = g & 32767, i = r >> 6, j = r & 63;
        const float* a  = Wq1 + (h*NDQ + i)*ND1;
        const float* bb = Wq2 + h*ND1*ND2 + j;
        float s = 0.f;
        for (int k = 0; k < ND1; ++k) s += a[k] * bb[k*ND2];
        WQC[(h*NDQ + i)*ND2 + j] = s;
        return;
    }
    g -= NH*NDQ*ND2;
    if (g < 2*NH*NDF*ND2) {                     // Wfc (hi+lo) / Wvc (hi), transposed image
        int which = (g >= NH*NDF*ND2);
        int r0 = g & (NH*NDF*ND2 - 1);
        int h = r0 >> 13, r = r0 & 8191, i = r >> 6, j = r & 63;
        const float* W1 = (which ? Wv1 : Wf1) + (h*NDF + i)*ND1;
        const float* W2 = (which ? Wv2 : Wf2) + h*ND1*ND2 + j;
        float s = 0.f;
        for (int k = 0; k < ND1; ++k) s += W1[k] * W2[k*ND2];
        short hi = f2bf(s);
        short lo = f2bf(s - bf2f(hi));
        __hip_bfloat16* img = WIMG + (size_t)((h*3 + (which ? 2 : 0))*ND2 + j)*KP + i; // [col=j][k=i]
        ((short*)img)[0] = hi;
        if (!which) ((short*)img)[ND2*KP] = lo;  // Wf lo slot
        return;
    }
    g -= 2*NH*NDF*ND2;
    if (g < NH*ND2) {                           // bqc = bq1@Wq2 + bq2
        int h = g >> 6, j = g & 63;
        float s = bq2[h*ND2 + j];
        for (int k = 0; k < ND1; ++k) s += bq1[h*ND1 + k] * Wq2[(h*ND1 + k)*ND2 + j];
        BQC[g] = s; return;
    }
    g -= NH*ND2;
    if (g < NH*ND2) {
        int h = g >> 6, j = g & 63;
        float s = bf2[h*ND2 + j];
        for (int k = 0; k < ND1; ++k) s += bf1[h*ND1 + k] * Wf2[(h*ND1 + k)*ND2 + j];
        BFC[g] = s; return;
    }
    g -= NH*ND2;
    if (g < NH*ND2) {
        int h = g >> 6, j = g & 63;
        float s = bv2[h*ND2 + j];
        for (int k = 0; k < ND1; ++k) s += bv1[h*ND1 + k] * Wv2[(h*ND1 + k)*ND2 + j];
        BVC[g] = s; return;
    }
}

// ---------------- K2: fq = silu(q @ Wqc + bqc) ----------------
__global__ __launch_bounds__(256) void k_fq(
    const float* __restrict__ query, const float* __restrict__ WQC,
    const float* __restrict__ BQC, float* __restrict__ FQ)
{
    __shared__ __align__(16) float qS[2*NDQ];
    const int t = threadIdx.x;
    const int b0 = blockIdx.x * 2;
    {
        const float4* src = (const float4*)(query + (size_t)b0 * NDQ);
        ((float4*)qS)[t] = src[t];              // 256 float4 = 2 x 512 floats
    }
    __syncthreads();
    const int h = t >> 6, d = t & 63;
    float s0, s1;
    s0 = s1 = BQC[h*ND2 + d];
    const float* wp = WQC + (size_t)h*NDQ*ND2 + d;
    #pragma unroll 16
    for (int i = 0; i < NDQ; ++i) {
        float wv = wp[i*ND2];
        s0 += qS[i]       * wv;
        s1 += qS[NDQ + i] * wv;
    }
    float* o = FQ + ((size_t)h*NB + b0)*ND2 + d;
    o[0]   = fsilu(s0);
    o[ND2] = fsilu(s1);
}

// ---------------- K3: main fused attention ----------------
// 832 threads (13 warps), one M-tile/warp, one b per block. LDS weights are
// DOUBLE-BUFFERED with a rotation swizzle (granule g of row r stored at
// g^ = (g + 2*(r&7)) & 15) -> every ds_read_b128 / staging write hits each
// bank-group with exactly 8 lanes (conflict floor). Barrier schedule: 1
// initial + 1 per head: each phase = {merge prev head (1 warp) || issue
// next-head stage loads || compute head h || ds_write staged regs} ->
// barrier. FQ/BFC/BVC staged to LDS once at block start.
__global__ __launch_bounds__(NT) void k_main(
    const float* __restrict__ fact,
    const int* __restrict__ mask,
    const float* __restrict__ mmc,
    const float* __restrict__ tau1,
    const float* __restrict__ tau2,
    const float* __restrict__ FQ,
    const float* __restrict__ BFC,
    const float* __restrict__ BVC,
    const __hip_bfloat16* __restrict__ WIMG,
    float* __restrict__ out)
{
    __shared__ __align__(16) __hip_bfloat16 wS[2][3*ND2*KP];  // 2 x 49152 B
    __shared__ __align__(16) float pS[2][NW][132];            // ping-pong: m, s, oE[64], oS[64]
    __shared__ __align__(16) float fqS[NH][ND2];              // 1 KB
    __shared__ __align__(16) float bfcS[NH][ND2];             // 1 KB
    __shared__ __align__(16) float bvcS[NH][ND2];             // 1 KB

    const int t    = threadIdx.x;
    const int b    = blockIdx.x;
    const int w    = t >> 6;                    // 0..12 = M-tile index
    const int lane = t & 63;
    const int a15  = lane & 15;
    const int quad = lane >> 4;
    const int qrot = quad + 2*(a15 & 7);        // read-side swizzle base

    const int bL = b * NL;

    // ---- issue head-0 staging loads (consumed after A-convert) ----
    float4 sreg[4];
    {
        const float4* src = (const float4*)WIMG;
        #pragma unroll
        for (int k = 0; k < 4; ++k) { int i = t + k*NT; if (i < SGRAN) sreg[k] = src[i]; }
    }
    // ---- issue per-head constant loads (FQ/BFC/BVC -> LDS later) ----
    float cval = 0.f;
    if (t < 256)       cval = FQ[(((size_t)(t >> 6))*NB + b)*ND2 + (t & 63)];
    else if (t < 512)  cval = BFC[t - 256];
    else if (t < 768)  cval = BVC[t - 512];
    // ---- head-invariant per-row data (mask penalty + cosine terms) ----
    float mkv[4], c0v[4], c1v[4];
    {
        int rbase = w*16 + quad*4;
        for (int rg = 0; rg < 4; ++rg) {
            int r = rbase + rg;
            if (r < NL) {
                mkv[rg] = 1e9f * (1.0f - (float)mask[bL + r]);
                c0v[rg] = mmc[bL + r];
                c1v[rg] = mmc[NB*NL + bL + r];
            } else { mkv[rg] = 0.f; c0v[rg] = 0.f; c1v[rg] = 0.f; }
        }
    }

    // ---- A fragments: this warp's 16 fact rows, hi/lo bf16 (heavy VALU;
    //      hides the latency of all loads issued above) ----
    short8 afh[4], afl[4];
    const short8 zero8 = {0,0,0,0,0,0,0,0};
    {
        int row = w*16 + a15;
        for (int kk = 0; kk < 4; ++kk) {
            short8 vh = zero8, vl = zero8;
            if (row < NL) {
                const float* p = fact + ((size_t)(bL + row))*NDF + kk*32 + quad*8;
                float4 x0 = *(const float4*)p;
                float4 x1 = *(const float4*)(p + 4);
                float v[8] = {x0.x, x0.y, x0.z, x0.w, x1.x, x1.y, x1.z, x1.w};
                for (int j = 0; j < 8; ++j) {
                    short hs = f2bf(v[j]);
                    vh[j] = hs;
                    vl[j] = f2bf(v[j] - bf2f(hs));
                }
            }
            afh[kk] = vh;
            afl[kk] = vl;
        }
    }

    // ---- write staged data: head-0 weights (swizzled) + constants ----
    {
        float4* dst = (float4*)&wS[0][0];
        #pragma unroll
        for (int k = 0; k < 4; ++k) {
            int i = t + k*NT;
            if (i < SGRAN) {
                int row = i >> 4, g = i & 15;
                dst[row*16 + ((g + 2*(row & 7)) & 15)] = sreg[k];
            }
        }
    }
    if (t < 256)       ((float*)fqS)[t]        = cval;
    else if (t < 512)  ((float*)bfcS)[t - 256] = cval;
    else if (t < 768)  ((float*)bvcS)[t - 512] = cval;
    __syncthreads();

    const f32x4 zf = {0.f, 0.f, 0.f, 0.f};

    for (int h = 0; h < NH; ++h) {
        // ---- issue next-head staging loads first (latency hides under compute) ----
        if (h + 1 < NH) {
            const float4* src = (const float4*)(WIMG + (size_t)((h+1)*3)*ND2*KP);
            #pragma unroll
            for (int k = 0; k < 4; ++k) { int i = t + k*NT; if (i < SGRAN) sreg[k] = src[i]; }
        }
        // ---- merge of previous head by one dedicated warp (9..11) ----
        if (h > 0 && w == 8 + h) {
            const int ps = (h - 1) & 1;
            float M = pS[ps][0][0];
            for (int ww = 1; ww < NW; ++ww) M = fmaxf(M, pS[ps][ww][0]);
            float den = 0.f, num = 0.f, s1 = 0.f;
            for (int ww = 0; ww < NW; ++ww) {
                float e = __expf(pS[ps][ww][0] - M);
                den += e * pS[ps][ww][1];
                num += e * pS[ps][ww][2 + lane];
                s1  += pS[ps][ww][66 + lane];
            }
            out[(size_t)b*(NH*ND2) + (h-1)*ND2 + lane] = num * __fdividef(1.f, den) + 1e-7f * s1;
        }

        const float rt1a = __fdividef(1.f, tau1[h]);
        const float rt1b = __fdividef(1.f, tau1[NH + h]);
        const float t20 = tau2[h];
        const float t21 = tau2[NH + h];
        const float t22 = tau2[2*NH + h];

        float fqv[4], bfcv[4];
        for (int nt = 0; nt < 4; ++nt) {
            fqv[nt]  = fqS[h][nt*16 + a15];
            bfcv[nt] = bfcS[h][nt*16 + a15];
        }

        const __hip_bfloat16* wb = &wS[h & 1][0];

        // ---- ff GEMM, 3 passes: f_hi*w_hi + f_hi*w_lo + f_lo*w_hi ----
        f32x4 acc[4];
        for (int nt = 0; nt < 4; ++nt) acc[nt] = zf;
        __builtin_amdgcn_s_setprio(1);
        for (int kk = 0; kk < 4; ++kk) {
            const int gk = ((kk*4 + qrot) & 15) << 3;   // swizzled granule (halfwords)
            short8 bh[4], bl[4];
            for (int nt = 0; nt < 4; ++nt) {
                const __hip_bfloat16* p = wb + (nt*16 + a15)*KP + gk;
                bh[nt] = *(const short8*)p;
                bl[nt] = *(const short8*)(p + ND2*KP);
            }
            for (int nt = 0; nt < 4; ++nt) {
                acc[nt] = __builtin_amdgcn_mfma_f32_16x16x32_bf16(afh[kk], bh[nt], acc[nt], 0, 0, 0);
                acc[nt] = __builtin_amdgcn_mfma_f32_16x16x32_bf16(afh[kk], bl[nt], acc[nt], 0, 0, 0);
                acc[nt] = __builtin_amdgcn_mfma_f32_16x16x32_bf16(afl[kk], bh[nt], acc[nt], 0, 0, 0);
            }
        }
        __builtin_amdgcn_s_setprio(0);

        // ---- epilogue: silu, dot with fq (butterfly -> row-dot in all 16
        //      lanes of each quad-group), mask + cosine bias -> logits ----
        float lg[4];
        for (int rg = 0; rg < 4; ++rg) {
            float l = -3.0e38f;
            float s = 0.f;
            for (int nt = 0; nt < 4; ++nt)
                s += fsilu(acc[nt][rg] + bfcv[nt]) * fqv[nt];
            s += __shfl_xor(s, 1);
            s += __shfl_xor(s, 2);
            s += __shfl_xor(s, 4);
            s += __shfl_xor(s, 8);
            int r = w*16 + quad*4 + rg;
            if (r < NL) {
                float dv = s - mkv[rg];
                float bias = c0v[rg]*rt1a + c1v[rg]*rt1b;
                l = t20*dv + t21*bias + t22*dv*bias;
            }
            lg[rg] = l;
        }

        // ---- warp-local softmax over own 16 rows ----
        float m = fmaxf(fmaxf(lg[0], lg[1]), fmaxf(lg[2], lg[3]));
        m = fmaxf(m, __shfl_xor(m, 16));
        m = fmaxf(m, __shfl_xor(m, 32));
        float sw = 0.f;
        for (int rg = 0; rg < 4; ++rg) {
            float p = __expf(lg[rg] - m);       // invalid rows underflow to 0
            lg[rg] = p;
            sw += p;
        }
        sw += __shfl_xor(sw, 16);
        sw += __shfl_xor(sw, 32);

        // ---- fv GEMM: single hi*hi pass (slot 2), reuse acc ----
        for (int nt = 0; nt < 4; ++nt) acc[nt] = zf;
        __builtin_amdgcn_s_setprio(1);
        for (int kk = 0; kk < 4; ++kk) {
            const int gk = ((kk*4 + qrot) & 15) << 3;
            short8 bv[4];
            for (int nt = 0; nt < 4; ++nt)
                bv[nt] = *(const short8*)(wb + (2*ND2 + nt*16 + a15)*KP + gk);
            for (int nt = 0; nt < 4; ++nt)
                acc[nt] = __builtin_amdgcn_mfma_f32_16x16x32_bf16(afh[kk], bv[nt], acc[nt], 0, 0, 0);
        }
        __builtin_amdgcn_s_setprio(0);

        // ---- AV: oE = sum p*silu(fv), oS = sum silu(fv) (for the +1e-7 term) ----
        float bvcv[4];
        for (int nt = 0; nt < 4; ++nt) bvcv[nt] = bvcS[h][nt*16 + a15];
        float oE[4] = {0.f,0.f,0.f,0.f}, oS[4] = {0.f,0.f,0.f,0.f};
        for (int rg = 0; rg < 4; ++rg) {
            float p = lg[rg];
            int r = w*16 + quad*4 + rg;
            float vm = (r < NL) ? 1.f : 0.f;
            for (int nt = 0; nt < 4; ++nt) {
                float sv = fsilu(acc[nt][rg] + bvcv[nt]);
                oE[nt] += p * sv;
                oS[nt] += vm * sv;
            }
        }
        for (int nt = 0; nt < 4; ++nt) {
            oE[nt] += __shfl_xor(oE[nt], 16);
            oE[nt] += __shfl_xor(oE[nt], 32);
            oS[nt] += __shfl_xor(oS[nt], 16);
            oS[nt] += __shfl_xor(oS[nt], 32);
        }
        if (lane == 0) { pS[h & 1][w][0] = m; pS[h & 1][w][1] = sw; }
        if (quad == 0)
            for (int nt = 0; nt < 4; ++nt) {
                pS[h & 1][w][2  + nt*16 + a15] = oE[nt];
                pS[h & 1][w][66 + nt*16 + a15] = oS[nt];
            }

        // ---- write next-head staged weights (swizzled) ----
        if (h + 1 < NH) {
            float4* dst = (float4*)&wS[(h+1) & 1][0];
            #pragma unroll
            for (int k = 0; k < 4; ++k) {
                int i = t + k*NT;
                if (i < SGRAN) {
                    int row = i >> 4, g = i & 15;
                    dst[row*16 + ((g + 2*(row & 7)) & 15)] = sreg[k];
                }
            }
        }
        __syncthreads();                        // pS[h&1] ready; wS[(h+1)&1] staged
    }

    // ---- final merge (head 3) by warp 12 ----
    if (w == 12) {
        const int ps = (NH - 1) & 1;
        float M = pS[ps][0][0];
        for (int ww = 1; ww < NW; ++ww) M = fmaxf(M, pS[ps][ww][0]);
        float den = 0.f, num = 0.f, s1 = 0.f;
        for (int ww = 0; ww < NW; ++ww) {
            float e = __expf(pS[ps][ww][0] - M);
            den += e * pS[ps][ww][1];
            num += e * pS[ps][ww][2 + lane];
            s1  += pS[ps][ww][66 + lane];
        }
        out[(size_t)b*(NH*ND2) + (NH-1)*ND2 + lane] = num * __fdividef(1.f, den) + 1e-7f * s1;
    }
}

extern "C" void kernel_launch(void* const* d_in, const int* in_sizes, int n_in,
                              void* d_out, int out_size, void* d_ws, size_t ws_size,
                              hipStream_t stream) {
    const float* query = (const float*)d_in[0];
    const float* fact  = (const float*)d_in[1];
    const int*   maskp = (const int*)d_in[2];
    const float* mmc   = (const float*)d_in[3];
    const float* Wq1 = (const float*)d_in[4];
    const float* bq1 = (const float*)d_in[5];
    const float* Wq2 = (const float*)d_in[6];
    const float* bq2 = (const float*)d_in[7];
    const float* Wf1 = (const float*)d_in[8];
    const float* bf1 = (const float*)d_in[9];
    const float* Wf2 = (const float*)d_in[10];
    const float* bf2 = (const float*)d_in[11];
    const float* Wv1 = (const float*)d_in[12];
    const float* bv1 = (const float*)d_in[13];
    const float* Wv2 = (const float*)d_in[14];
    const float* bv2 = (const float*)d_in[15];
    const float* tau1 = (const float*)d_in[16];
    const float* tau2 = (const float*)d_in[17];

    char* ws = (char*)d_ws;
    float*          WQC  = (float*)(ws + OFF_WQC);
    float*          BQC  = (float*)(ws + OFF_BQC);
    float*          FQ   = (float*)(ws + OFF_FQ);
    __hip_bfloat16* WIMG = (__hip_bfloat16*)(ws + OFF_WIMG);
    float*          BFC  = (float*)(ws + OFF_BFC);
    float*          BVC  = (float*)(ws + OFF_BVC);

    k_combine<<<771, 256, 0, stream>>>(Wq1, bq1, Wq2, bq2, Wf1, bf1, Wf2, bf2,
                                       Wv1, bv1, Wv2, bv2, WQC, BQC, WIMG, BFC, BVC);
    k_fq<<<NB/2, 256, 0, stream>>>(query, WQC, BQC, FQ);
    k_main<<<NB, NT, 0, stream>>>(fact, maskp, mmc, tau1, tau2, FQ, BFC, BVC, WIMG,
                                  (float*)d_out);
}

// Round 6
// 344.251 us; speedup vs baseline: 1.6623x; 1.0504x over previous
//
#include <hip/hip_runtime.h>
#include <hip/hip_bf16.h>

typedef __attribute__((ext_vector_type(8))) short short8;   // 8 bf16 (4 VGPRs)
typedef __attribute__((ext_vector_type(4))) float f32x4;    // MFMA acc

#define NH   4
#define NB   1024
#define NL   200
#define NDQ  512
#define NDF  128
#define ND1  128
#define ND2  64
#define KP   128            // k-stride (bf16 elems); conflicts handled by rotation swizzle
#define NW   13             // active warps = M-tiles (13*16 = 208 >= 200 rows)
#define NT   (NW*64)        // 832 threads
#define HIMG (3*ND2*KP*2)   // bytes per head weight image (49152)
#define SGRAN (3*ND2*16)    // 3072 float4 granules per head image

// workspace layout (bytes)
#define OFF_WQC   0                                    // fp32 [H][512][64]   524288
#define OFF_BQC   (NH*NDQ*ND2*4)                       // fp32 [H][64]
#define OFF_FQ    (OFF_BQC + NH*ND2*4)                 // fp32 [H][B][64]
#define OFF_WIMG  (OFF_FQ + NH*NB*ND2*4)               // bf16 [H][3][64][KP] (slots: Wf_hi, Wf_lo, Wv_hi)
#define OFF_BFC   (OFF_WIMG + NH*HIMG)                 // fp32 [H][64]
#define OFF_BVC   (OFF_BFC + NH*ND2*4)                 // fp32 [H][64]

// global->LDS DMA: per-lane GLOBAL address, wave-uniform LDS base + lane*16
#define GLOAD_LDS16(gp, lp) __builtin_amdgcn_global_load_lds(                 \
    (const __attribute__((address_space(1))) void*)(gp),                      \
    (__attribute__((address_space(3))) void*)(lp), 16, 0, 0)

__device__ inline short f2bf(float f) {                // RN-even fp32 -> bf16 bits
    union { float f; unsigned u; } v; v.f = f;
    unsigned r = (v.u + 0x7FFFu + ((v.u >> 16) & 1u)) >> 16;
    return (short)r;
}
__device__ inline float bf2f(short s) {
    union { unsigned u; float f; } v; v.u = ((unsigned)(unsigned short)s) << 16;
    return v.f;
}
__device__ inline float fsilu(float z) {               // fast silu
    return z * __fdividef(1.f, 1.f + __expf(-z));
}

// ---------------- K1: fuse weights (identity between FC layers) ----------------
__global__ __launch_bounds__(256) void k_combine(
    const float* __restrict__ Wq1, const float* __restrict__ bq1,
    const float* __restrict__ Wq2, const float* __restrict__ bq2,
    const float* __restrict__ Wf1, const float* __restrict__ bf1,
    const float* __restrict__ Wf2, const float* __restrict__ bf2,
    const float* __restrict__ Wv1, const float* __restrict__ bv1,
    const float* __restrict__ Wv2, const float* __restrict__ bv2,
    float* __restrict__ WQC, float* __restrict__ BQC,
    __hip_bfloat16* __restrict__ WIMG, float* __restrict__ BFC, float* __restrict__ BVC)
{
    int g = blockIdx.x * 256 + threadIdx.x;
    if (g < NH*NDQ*ND2) {                       // Wqc = Wq1@Wq2 (fp32 exact)
        int h = g >> 15, r = g & 32767, i = r >> 6, j = r & 63;
        const float* a  = Wq1 + (h*NDQ + i)*ND1;
        const float* bb = Wq2 + h*ND1*ND2 + j;
        float s = 0.f;
        for (int k = 0; k < ND1; ++k) s += a[k] * bb[k*ND2];
        WQC[(h*NDQ + i)*ND2 + j] = s;
        return;
    }
    g -= NH*NDQ*ND2;
    if (g < 2*NH*NDF*ND2) {                     // Wfc (hi+lo) / Wvc (hi), transposed image
        int which = (g >= NH*NDF*ND2);
        int r0 = g & (NH*NDF*ND2 - 1);
        int h = r0 >> 13, r = r0 & 8191, i = r >> 6, j = r & 63;
        const float* W1 = (which ? Wv1 : Wf1) + (h*NDF + i)*ND1;
        const float* W2 = (which ? Wv2 : Wf2) + h*ND1*ND2 + j;
        float s = 0.f;
        for (int k = 0; k < ND1; ++k) s += W1[k] * W2[k*ND2];
        short hi = f2bf(s);
        short lo = f2bf(s - bf2f(hi));
        __hip_bfloat16* img = WIMG + (size_t)((h*3 + (which ? 2 : 0))*ND2 + j)*KP + i; // [col=j][k=i]
        ((short*)img)[0] = hi;
        if (!which) ((short*)img)[ND2*KP] = lo;  // Wf lo slot
        return;
    }
    g -= 2*NH*NDF*ND2;
    if (g < NH*ND2) {                           // bqc = bq1@Wq2 + bq2
        int h = g >> 6, j = g & 63;
        float s = bq2[h*ND2 + j];
        for (int k = 0; k < ND1; ++k) s += bq1[h*ND1 + k] * Wq2[(h*ND1 + k)*ND2 + j];
        BQC[g] = s; return;
    }
    g -= NH*ND2;
    if (g < NH*ND2) {
        int h = g >> 6, j = g & 63;
        float s = bf2[h*ND2 + j];
        for (int k = 0; k < ND1; ++k) s += bf1[h*ND1 + k] * Wf2[(h*ND1 + k)*ND2 + j];
        BFC[g] = s; return;
    }
    g -= NH*ND2;
    if (g < NH*ND2) {
        int h = g >> 6, j = g & 63;
        float s = bv2[h*ND2 + j];
        for (int k = 0; k < ND1; ++k) s += bv1[h*ND1 + k] * Wv2[(h*ND1 + k)*ND2 + j];
        BVC[g] = s; return;
    }
}

// ---------------- K2: fq = silu(q @ Wqc + bqc) ----------------
__global__ __launch_bounds__(256) void k_fq(
    const float* __restrict__ query, const float* __restrict__ WQC,
    const float* __restrict__ BQC, float* __restrict__ FQ)
{
    __shared__ __align__(16) float qS[2*NDQ];
    const int t = threadIdx.x;
    const int b0 = blockIdx.x * 2;
    {
        const float4* src = (const float4*)(query + (size_t)b0 * NDQ);
        ((float4*)qS)[t] = src[t];              // 256 float4 = 2 x 512 floats
    }
    __syncthreads();
    const int h = t >> 6, d = t & 63;
    float s0, s1;
    s0 = s1 = BQC[h*ND2 + d];
    const float* wp = WQC + (size_t)h*NDQ*ND2 + d;
    #pragma unroll 16
    for (int i = 0; i < NDQ; ++i) {
        float wv = wp[i*ND2];
        s0 += qS[i]       * wv;
        s1 += qS[NDQ + i] * wv;
    }
    float* o = FQ + ((size_t)h*NB + b0)*ND2 + d;
    o[0]   = fsilu(s0);
    o[ND2] = fsilu(s1);
}

// ---------------- K3: main fused attention ----------------
// 832 threads (13 warps), one M-tile/warp, one b per block.
// __launch_bounds__(NT,4): only 1 block/CU is schedulable anyway (observed
// R2/R3/R5), so allow 128 VGPR -> no spill (R5 spilled 150 MB at cap 64).
// Weight staging via global_load_lds DMA: linear LDS dest, per-lane
// INVERSE-rotation-swizzled global source -> LDS image identical to R5's
// swizzled layout (reads stay conflict-free), zero staging VGPRs/VALU.
// Double-buffered; barriers: 1 initial + 1 per head.
__global__ __launch_bounds__(NT, 4) void k_main(
    const float* __restrict__ fact,
    const int* __restrict__ mask,
    const float* __restrict__ mmc,
    const float* __restrict__ tau1,
    const float* __restrict__ tau2,
    const float* __restrict__ FQ,
    const float* __restrict__ BFC,
    const float* __restrict__ BVC,
    const __hip_bfloat16* __restrict__ WIMG,
    float* __restrict__ out)
{
    __shared__ __align__(16) __hip_bfloat16 wS[2][3*ND2*KP];  // 2 x 49152 B
    __shared__ __align__(16) float pS[2][NW][132];            // ping-pong: m, s, oE[64], oS[64]
    __shared__ __align__(16) float fqS[NH][ND2];              // 1 KB
    __shared__ __align__(16) float bfcS[NH][ND2];             // 1 KB
    __shared__ __align__(16) float bvcS[NH][ND2];             // 1 KB

    const int t    = threadIdx.x;
    const int b    = blockIdx.x;
    const int w    = t >> 6;                    // 0..12 = M-tile index
    const int lane = t & 63;
    const int a15  = lane & 15;
    const int quad = lane >> 4;
    const int qrot = quad + 2*(a15 & 7);        // read-side swizzle base

    const int bL = b * NL;

    // ---- DMA staging setup: wave w owns float4-chunks w*4..w*4+3 (<48).
    //      LDS slot i = c*64 + lane receives global granule row*16 + g with
    //      g = ((i&15) - 2*(row&7)) & 15, row = i>>4  (inverse of R5 swizzle).
    int srcOff[4], ldsByte[4];
    bool cOk[4];
    #pragma unroll
    for (int j = 0; j < 4; ++j) {
        int c = w*4 + j;
        cOk[j] = (c < SGRAN/64);
        int i = c*64 + lane;
        int row = i >> 4, gp = i & 15;
        int g = (gp - 2*(row & 7)) & 15;
        srcOff[j] = (row*16 + g) * 16;          // bytes within head image
        ldsByte[j] = c * 1024;                  // wave-uniform LDS base (bytes)
    }
    // ---- issue head-0 DMA immediately (hides under prologue) ----
    #pragma unroll
    for (int j = 0; j < 4; ++j)
        if (cOk[j])
            GLOAD_LDS16((const char*)WIMG + srcOff[j], (char*)&wS[0][0] + ldsByte[j]);

    // ---- per-head constant loads (FQ/BFC/BVC -> LDS) ----
    float cval = 0.f;
    if (t < 256)       cval = FQ[(((size_t)(t >> 6))*NB + b)*ND2 + (t & 63)];
    else if (t < 512)  cval = BFC[t - 256];
    else if (t < 768)  cval = BVC[t - 512];
    // ---- head-invariant per-row data (mask penalty + cosine terms) ----
    float mkv[4], c0v[4], c1v[4];
    {
        int rbase = w*16 + quad*4;
        for (int rg = 0; rg < 4; ++rg) {
            int r = rbase + rg;
            if (r < NL) {
                mkv[rg] = 1e9f * (1.0f - (float)mask[bL + r]);
                c0v[rg] = mmc[bL + r];
                c1v[rg] = mmc[NB*NL + bL + r];
            } else { mkv[rg] = 0.f; c0v[rg] = 0.f; c1v[rg] = 0.f; }
        }
    }

    // ---- A fragments: this warp's 16 fact rows, hi/lo bf16 (heavy VALU;
    //      hides the latency of the DMA + loads issued above) ----
    short8 afh[4], afl[4];
    const short8 zero8 = {0,0,0,0,0,0,0,0};
    {
        int row = w*16 + a15;
        for (int kk = 0; kk < 4; ++kk) {
            short8 vh = zero8, vl = zero8;
            if (row < NL) {
                const float* p = fact + ((size_t)(bL + row))*NDF + kk*32 + quad*8;
                float4 x0 = *(const float4*)p;
                float4 x1 = *(const float4*)(p + 4);
                float v[8] = {x0.x, x0.y, x0.z, x0.w, x1.x, x1.y, x1.z, x1.w};
                for (int j = 0; j < 8; ++j) {
                    short hs = f2bf(v[j]);
                    vh[j] = hs;
                    vl[j] = f2bf(v[j] - bf2f(hs));
                }
            }
            afh[kk] = vh;
            afl[kk] = vl;
        }
    }

    if (t < 256)       ((float*)fqS)[t]        = cval;
    else if (t < 512)  ((float*)bfcS)[t - 256] = cval;
    else if (t < 768)  ((float*)bvcS)[t - 512] = cval;
    __syncthreads();                            // drains DMA (vmcnt) + LDS writes

    const f32x4 zf = {0.f, 0.f, 0.f, 0.f};

    for (int h = 0; h < NH; ++h) {
        // ---- issue next-head DMA first (latency hides under compute) ----
        if (h + 1 < NH) {
            const char* hb = (const char*)WIMG + (size_t)(h+1)*HIMG;
            char* lb = (char*)&wS[(h+1) & 1][0];
            #pragma unroll
            for (int j = 0; j < 4; ++j)
                if (cOk[j]) GLOAD_LDS16(hb + srcOff[j], lb + ldsByte[j]);
        }
        // ---- merge of previous head by one dedicated warp (9..11) ----
        if (h > 0 && w == 8 + h) {
            const int ps = (h - 1) & 1;
            float M = pS[ps][0][0];
            for (int ww = 1; ww < NW; ++ww) M = fmaxf(M, pS[ps][ww][0]);
            float den = 0.f, num = 0.f, s1 = 0.f;
            for (int ww = 0; ww < NW; ++ww) {
                float e = __expf(pS[ps][ww][0] - M);
                den += e * pS[ps][ww][1];
                num += e * pS[ps][ww][2 + lane];
                s1  += pS[ps][ww][66 + lane];
            }
            out[(size_t)b*(NH*ND2) + (h-1)*ND2 + lane] = num * __fdividef(1.f, den) + 1e-7f * s1;
        }

        const float rt1a = __fdividef(1.f, tau1[h]);
        const float rt1b = __fdividef(1.f, tau1[NH + h]);
        const float t20 = tau2[h];
        const float t21 = tau2[NH + h];
        const float t22 = tau2[2*NH + h];

        float fqv[4], bfcv[4];
        for (int nt = 0; nt < 4; ++nt) {
            fqv[nt]  = fqS[h][nt*16 + a15];
            bfcv[nt] = bfcS[h][nt*16 + a15];
        }

        const __hip_bfloat16* wb = &wS[h & 1][0];

        // ---- ff GEMM, 3 passes: f_hi*w_hi + f_hi*w_lo + f_lo*w_hi ----
        f32x4 acc[4];
        for (int nt = 0; nt < 4; ++nt) acc[nt] = zf;
        __builtin_amdgcn_s_setprio(1);
        for (int kk = 0; kk < 4; ++kk) {
            const int gk = ((kk*4 + qrot) & 15) << 3;   // swizzled granule (halfwords)
            short8 bh[4], bl[4];
            for (int nt = 0; nt < 4; ++nt) {
                const __hip_bfloat16* p = wb + (nt*16 + a15)*KP + gk;
                bh[nt] = *(const short8*)p;
                bl[nt] = *(const short8*)(p + ND2*KP);
            }
            for (int nt = 0; nt < 4; ++nt) {
                acc[nt] = __builtin_amdgcn_mfma_f32_16x16x32_bf16(afh[kk], bh[nt], acc[nt], 0, 0, 0);
                acc[nt] = __builtin_amdgcn_mfma_f32_16x16x32_bf16(afh[kk], bl[nt], acc[nt], 0, 0, 0);
                acc[nt] = __builtin_amdgcn_mfma_f32_16x16x32_bf16(afl[kk], bh[nt], acc[nt], 0, 0, 0);
            }
        }
        __builtin_amdgcn_s_setprio(0);

        // ---- epilogue: silu, dot with fq (butterfly -> row-dot in all 16
        //      lanes of each quad-group), mask + cosine bias -> logits ----
        float lg[4];
        for (int rg = 0; rg < 4; ++rg) {
            float l = -3.0e38f;
            float s = 0.f;
            for (int nt = 0; nt < 4; ++nt)
                s += fsilu(acc[nt][rg] + bfcv[nt]) * fqv[nt];
            s += __shfl_xor(s, 1);
            s += __shfl_xor(s, 2);
            s += __shfl_xor(s, 4);
            s += __shfl_xor(s, 8);
            int r = w*16 + quad*4 + rg;
            if (r < NL) {
                float dv = s - mkv[rg];
                float bias = c0v[rg]*rt1a + c1v[rg]*rt1b;
                l = t20*dv + t21*bias + t22*dv*bias;
            }
            lg[rg] = l;
        }

        // ---- warp-local softmax over own 16 rows ----
        float m = fmaxf(fmaxf(lg[0], lg[1]), fmaxf(lg[2], lg[3]));
        m = fmaxf(m, __shfl_xor(m, 16));
        m = fmaxf(m, __shfl_xor(m, 32));
        float sw = 0.f;
        for (int rg = 0; rg < 4; ++rg) {
            float p = __expf(lg[rg] - m);       // invalid rows underflow to 0
            lg[rg] = p;
            sw += p;
        }
        sw += __shfl_xor(sw, 16);
        sw += __shfl_xor(sw, 32);

        // ---- fv GEMM: single hi*hi pass (slot 2), reuse acc ----
        for (int nt = 0; nt < 4; ++nt) acc[nt] = zf;
        __builtin_amdgcn_s_setprio(1);
        for (int kk = 0; kk < 4; ++kk) {
            const int gk = ((kk*4 + qrot) & 15) << 3;
            short8 bv[4];
            for (int nt = 0; nt < 4; ++nt)
                bv[nt] = *(const short8*)(wb + (2*ND2 + nt*16 + a15)*KP + gk);
            for (int nt = 0; nt < 4; ++nt)
                acc[nt] = __builtin_amdgcn_mfma_f32_16x16x32_bf16(afh[kk], bv[nt], acc[nt], 0, 0, 0);
        }
        __builtin_amdgcn_s_setprio(0);

        // ---- AV: oE = sum p*silu(fv), oS = sum silu(fv) (for the +1e-7 term) ----
        float bvcv[4];
        for (int nt = 0; nt < 4; ++nt) bvcv[nt] = bvcS[h][nt*16 + a15];
        float oE[4] = {0.f,0.f,0.f,0.f}, oS[4] = {0.f,0.f,0.f,0.f};
        for (int rg = 0; rg < 4; ++rg) {
            float p = lg[rg];
            int r = w*16 + quad*4 + rg;
            float vm = (r < NL) ? 1.f : 0.f;
            for (int nt = 0; nt < 4; ++nt) {
                float sv = fsilu(acc[nt][rg] + bvcv[nt]);
                oE[nt] += p * sv;
                oS[nt] += vm * sv;
            }
        }
        for (int nt = 0; nt < 4; ++nt) {
            oE[nt] += __shfl_xor(oE[nt], 16);
            oE[nt] += __shfl_xor(oE[nt], 32);
            oS[nt] += __shfl_xor(oS[nt], 16);
            oS[nt] += __shfl_xor(oS[nt], 32);
        }
        if (lane == 0) { pS[h & 1][w][0] = m; pS[h & 1][w][1] = sw; }
        if (quad == 0)
            for (int nt = 0; nt < 4; ++nt) {
                pS[h & 1][w][2  + nt*16 + a15] = oE[nt];
                pS[h & 1][w][66 + nt*16 + a15] = oS[nt];
            }
        __syncthreads();                        // pS[h&1] ready; DMA for (h+1) drained
    }

    // ---- final merge (head 3) by warp 12 ----
    if (w == 12) {
        const int ps = (NH - 1) & 1;
        float M = pS[ps][0][0];
        for (int ww = 1; ww < NW; ++ww) M = fmaxf(M, pS[ps][ww][0]);
        float den = 0.f, num = 0.f, s1 = 0.f;
        for (int ww = 0; ww < NW; ++ww) {
            float e = __expf(pS[ps][ww][0] - M);
            den += e * pS[ps][ww][1];
            num += e * pS[ps][ww][2 + lane];
            s1  += pS[ps][ww][66 + lane];
        }
        out[(size_t)b*(NH*ND2) + (NH-1)*ND2 + lane] = num * __fdividef(1.f, den) + 1e-7f * s1;
    }
}

extern "C" void kernel_launch(void* const* d_in, const int* in_sizes, int n_in,
                              void* d_out, int out_size, void* d_ws, size_t ws_size,
                              hipStream_t stream) {
    const float* query = (const float*)d_in[0];
    const float* fact  = (const float*)d_in[1];
    const int*   maskp = (const int*)d_in[2];
    const float* mmc   = (const float*)d_in[3];
    const float* Wq1 = (const float*)d_in[4];
    const float* bq1 = (const float*)d_in[5];
    const float* Wq2 = (const float*)d_in[6];
    const float* bq2 = (const float*)d_in[7];
    const float* Wf1 = (const float*)d_in[8];
    const float* bf1 = (const float*)d_in[9];
    const float* Wf2 = (const float*)d_in[10];
    const float* bf2 = (const float*)d_in[11];
    const float* Wv1 = (const float*)d_in[12];
    const float* bv1 = (const float*)d_in[13];
    const float* Wv2 = (const float*)d_in[14];
    const float* bv2 = (const float*)d_in[15];
    const float* tau1 = (const float*)d_in[16];
    const float* tau2 = (const float*)d_in[17];

    char* ws = (char*)d_ws;
    float*          WQC  = (float*)(ws + OFF_WQC);
    float*          BQC  = (float*)(ws + OFF_BQC);
    float*          FQ   = (float*)(ws + OFF_FQ);
    __hip_bfloat16* WIMG = (__hip_bfloat16*)(ws + OFF_WIMG);
    float*          BFC  = (float*)(ws + OFF_BFC);
    float*          BVC  = (float*)(ws + OFF_BVC);

    k_combine<<<771, 256, 0, stream>>>(Wq1, bq1, Wq2, bq2, Wf1, bf1, Wf2, bf2,
                                       Wv1, bv1, Wv2, bv2, WQC, BQC, WIMG, BFC, BVC);
    k_fq<<<NB/2, 256, 0, stream>>>(query, WQC, BQC, FQ);
    k_main<<<NB, NT, 0, stream>>>(fact, maskp, mmc, tau1, tau2, FQ, BFC, BVC, WIMG,
                                  (float*)d_out);
}

// Round 7
// 334.794 us; speedup vs baseline: 1.7093x; 1.0282x over previous
//
#include <hip/hip_runtime.h>
#include <hip/hip_bf16.h>

typedef __attribute__((ext_vector_type(8))) short short8;   // 8 bf16 (4 VGPRs)
typedef __attribute__((ext_vector_type(4))) float f32x4;    // MFMA acc

#define NH   4
#define NB   1024
#define NL   200
#define NDQ  512
#define NDF  128
#define ND1  128
#define ND2  64
#define KP   128            // k-stride (bf16 elems); conflicts handled by rotation swizzle
#define NW   13             // active warps = M-tiles (13*16 = 208 >= 200 rows)
#define NT   (NW*64)        // 832 threads
#define HIMG (3*ND2*KP*2)   // bytes per head weight image (49152)
#define SGRAN (3*ND2*16)    // 3072 float4 granules per head image

// workspace layout (bytes)
#define OFF_WQC   0                                    // fp32 [H][512][64]   524288
#define OFF_BQC   (NH*NDQ*ND2*4)                       // fp32 [H][64]
#define OFF_FQ    (OFF_BQC + NH*ND2*4)                 // fp32 [H][B][64]
#define OFF_WIMG  (OFF_FQ + NH*NB*ND2*4)               // bf16 [H][3][64][KP] (slots: Wf_hi, Wf_lo, Wv_hi)
#define OFF_BFC   (OFF_WIMG + NH*HIMG)                 // fp32 [H][64]
#define OFF_BVC   (OFF_BFC + NH*ND2*4)                 // fp32 [H][64]

// global->LDS DMA: per-lane GLOBAL address, wave-uniform LDS base + lane*16
#define GLOAD_LDS16(gp, lp) __builtin_amdgcn_global_load_lds(                 \
    (const __attribute__((address_space(1))) void*)(gp),                      \
    (__attribute__((address_space(3))) void*)(lp), 16, 0, 0)

__device__ inline short f2bf(float f) {                // RN-even fp32 -> bf16 bits
    union { float f; unsigned u; } v; v.f = f;
    unsigned r = (v.u + 0x7FFFu + ((v.u >> 16) & 1u)) >> 16;
    return (short)r;
}
__device__ inline float bf2f(short s) {
    union { unsigned u; float f; } v; v.u = ((unsigned)(unsigned short)s) << 16;
    return v.f;
}
__device__ inline float fsilu(float z) {               // fast silu
    return z * __fdividef(1.f, 1.f + __expf(-z));
}

// ---- cross-lane reductions on the VALU (no DS pipe, no 120-cy ds_bpermute) ----
template<int CTRL>
__device__ inline float dppf(float x) {                // DPP-moved copy of x
    return __int_as_float(__builtin_amdgcn_update_dpp(0, __float_as_int(x), CTRL, 0xF, 0xF, true));
}
// sum over each 16-lane row; partials are quad-uniform at each step, so the
// added values are bit-identical to the xor1/2/4/8 shfl ladder.
__device__ inline float red16_add(float s) {
    s += dppf<0xB1>(s);      // quad_perm [1,0,3,2]  (xor1)
    s += dppf<0x4E>(s);      // quad_perm [2,3,0,1]  (xor2)
    s += dppf<0x141>(s);     // row_half_mirror      (pairs 4-groups in 8)
    s += dppf<0x140>(s);     // row_mirror           (pairs 8-groups in 16)
    return s;
}
// gfx950 permlane swaps: with (x,x) args, p0/p1 hold the two paired rows
// replicated -> p0 op p1 = cross-row combine in ALL lanes (commutative -> bit-exact).
__device__ inline float swap16_add(float x) {
    auto p = __builtin_amdgcn_permlane16_swap(__float_as_uint(x), __float_as_uint(x), false, false);
    return __uint_as_float(p[0]) + __uint_as_float(p[1]);
}
__device__ inline float swap32_add(float x) {
    auto p = __builtin_amdgcn_permlane32_swap(__float_as_uint(x), __float_as_uint(x), false, false);
    return __uint_as_float(p[0]) + __uint_as_float(p[1]);
}
__device__ inline float swap16_max(float x) {
    auto p = __builtin_amdgcn_permlane16_swap(__float_as_uint(x), __float_as_uint(x), false, false);
    return fmaxf(__uint_as_float(p[0]), __uint_as_float(p[1]));
}
__device__ inline float swap32_max(float x) {
    auto p = __builtin_amdgcn_permlane32_swap(__float_as_uint(x), __float_as_uint(x), false, false);
    return fmaxf(__uint_as_float(p[0]), __uint_as_float(p[1]));
}

// ---------------- K1: fuse weights (identity between FC layers) ----------------
__global__ __launch_bounds__(256) void k_combine(
    const float* __restrict__ Wq1, const float* __restrict__ bq1,
    const float* __restrict__ Wq2, const float* __restrict__ bq2,
    const float* __restrict__ Wf1, const float* __restrict__ bf1,
    const float* __restrict__ Wf2, const float* __restrict__ bf2,
    const float* __restrict__ Wv1, const float* __restrict__ bv1,
    const float* __restrict__ Wv2, const float* __restrict__ bv2,
    float* __restrict__ WQC, float* __restrict__ BQC,
    __hip_bfloat16* __restrict__ WIMG, float* __restrict__ BFC, float* __restrict__ BVC)
{
    int g = blockIdx.x * 256 + threadIdx.x;
    if (g < NH*NDQ*ND2) {                       // Wqc = Wq1@Wq2 (fp32 exact)
        int h = g >> 15, r = g & 32767, i = r >> 6, j = r & 63;
        const float* a  = Wq1 + (h*NDQ + i)*ND1;
        const float* bb = Wq2 + h*ND1*ND2 + j;
        float s = 0.f;
        for (int k = 0; k < ND1; ++k) s += a[k] * bb[k*ND2];
        WQC[(h*NDQ + i)*ND2 + j] = s;
        return;
    }
    g -= NH*NDQ*ND2;
    if (g < 2*NH*NDF*ND2) {                     // Wfc (hi+lo) / Wvc (hi), transposed image
        int which = (g >= NH*NDF*ND2);
        int r0 = g & (NH*NDF*ND2 - 1);
        int h = r0 >> 13, r = r0 & 8191, i = r >> 6, j = r & 63;
        const float* W1 = (which ? Wv1 : Wf1) + (h*NDF + i)*ND1;
        const float* W2 = (which ? Wv2 : Wf2) + h*ND1*ND2 + j;
        float s = 0.f;
        for (int k = 0; k < ND1; ++k) s += W1[k] * W2[k*ND2];
        short hi = f2bf(s);
        short lo = f2bf(s - bf2f(hi));
        __hip_bfloat16* img = WIMG + (size_t)((h*3 + (which ? 2 : 0))*ND2 + j)*KP + i; // [col=j][k=i]
        ((short*)img)[0] = hi;
        if (!which) ((short*)img)[ND2*KP] = lo;  // Wf lo slot
        return;
    }
    g -= 2*NH*NDF*ND2;
    if (g < NH*ND2) {                           // bqc = bq1@Wq2 + bq2
        int h = g >> 6, j = g & 63;
        float s = bq2[h*ND2 + j];
        for (int k = 0; k < ND1; ++k) s += bq1[h*ND1 + k] * Wq2[(h*ND1 + k)*ND2 + j];
        BQC[g] = s; return;
    }
    g -= NH*ND2;
    if (g < NH*ND2) {
        int h = g >> 6, j = g & 63;
        float s = bf2[h*ND2 + j];
        for (int k = 0; k < ND1; ++k) s += bf1[h*ND1 + k] * Wf2[(h*ND1 + k)*ND2 + j];
        BFC[g] = s; return;
    }
    g -= NH*ND2;
    if (g < NH*ND2) {
        int h = g >> 6, j = g & 63;
        float s = bv2[h*ND2 + j];
        for (int k = 0; k < ND1; ++k) s += bv1[h*ND1 + k] * Wv2[(h*ND1 + k)*ND2 + j];
        BVC[g] = s; return;
    }
}

// ---------------- K2: fq = silu(q @ Wqc + bqc) ----------------
__global__ __launch_bounds__(256) void k_fq(
    const float* __restrict__ query, const float* __restrict__ WQC,
    const float* __restrict__ BQC, float* __restrict__ FQ)
{
    __shared__ __align__(16) float qS[2*NDQ];
    const int t = threadIdx.x;
    const int b0 = blockIdx.x * 2;
    {
        const float4* src = (const float4*)(query + (size_t)b0 * NDQ);
        ((float4*)qS)[t] = src[t];              // 256 float4 = 2 x 512 floats
    }
    __syncthreads();
    const int h = t >> 6, d = t & 63;
    float s0, s1;
    s0 = s1 = BQC[h*ND2 + d];
    const float* wp = WQC + (size_t)h*NDQ*ND2 + d;
    #pragma unroll 16
    for (int i = 0; i < NDQ; ++i) {
        float wv = wp[i*ND2];
        s0 += qS[i]       * wv;
        s1 += qS[NDQ + i] * wv;
    }
    float* o = FQ + ((size_t)h*NB + b0)*ND2 + d;
    o[0]   = fsilu(s0);
    o[ND2] = fsilu(s1);
}

// ---------------- K3: main fused attention ----------------
// 832 threads (13 warps), one M-tile/warp, one b per block.
// amdgpu_waves_per_eu(4,4): 13-wave block needs 4 waves on one SIMD -> true
// VGPR cap is 128; pinning min=max=4 stops the allocator from squeezing to 64
// and spilling (R6: 16 MB scratch at VGPR=64).
// All cross-lane reductions are VALU (DPP + gfx950 permlane swaps) -> the DS
// pipe only carries the GEMM ds_read_b128 stream; the 36 ds_bpermute
// (~120 cy each, dependent chains) per wave per phase are gone.
// Weight staging via global_load_lds DMA (inverse-rotation-swizzled source,
// conflict-free reads), double-buffered; 1 barrier per head.
__global__ __launch_bounds__(NT) __attribute__((amdgpu_waves_per_eu(4, 4))) void k_main(
    const float* __restrict__ fact,
    const int* __restrict__ mask,
    const float* __restrict__ mmc,
    const float* __restrict__ tau1,
    const float* __restrict__ tau2,
    const float* __restrict__ FQ,
    const float* __restrict__ BFC,
    const float* __restrict__ BVC,
    const __hip_bfloat16* __restrict__ WIMG,
    float* __restrict__ out)
{
    __shared__ __align__(16) __hip_bfloat16 wS[2][3*ND2*KP];  // 2 x 49152 B
    __shared__ __align__(16) float pS[2][NW][132];            // ping-pong: m, s, oE[64], oS[64]
    __shared__ __align__(16) float fqS[NH][ND2];              // 1 KB
    __shared__ __align__(16) float bfcS[NH][ND2];             // 1 KB
    __shared__ __align__(16) float bvcS[NH][ND2];             // 1 KB

    const int t    = threadIdx.x;
    const int b    = blockIdx.x;
    const int w    = t >> 6;                    // 0..12 = M-tile index
    const int lane = t & 63;
    const int a15  = lane & 15;
    const int quad = lane >> 4;
    const int qrot = quad + 2*(a15 & 7);        // read-side swizzle base

    const int bL = b * NL;

    // ---- DMA staging setup: wave w owns float4-chunks w*4..w*4+3 (<48).
    //      LDS slot i = c*64 + lane receives global granule row*16 + g with
    //      g = ((i&15) - 2*(row&7)) & 15, row = i>>4  (inverse of the swizzle).
    int srcOff[4], ldsByte[4];
    bool cOk[4];
    #pragma unroll
    for (int j = 0; j < 4; ++j) {
        int c = w*4 + j;
        cOk[j] = (c < SGRAN/64);
        int i = c*64 + lane;
        int row = i >> 4, gp = i & 15;
        int g = (gp - 2*(row & 7)) & 15;
        srcOff[j] = (row*16 + g) * 16;          // bytes within head image
        ldsByte[j] = c * 1024;                  // wave-uniform LDS base (bytes)
    }
    // ---- issue head-0 DMA immediately (hides under prologue) ----
    #pragma unroll
    for (int j = 0; j < 4; ++j)
        if (cOk[j])
            GLOAD_LDS16((const char*)WIMG + srcOff[j], (char*)&wS[0][0] + ldsByte[j]);

    // ---- per-head constant loads (FQ/BFC/BVC -> LDS) ----
    float cval = 0.f;
    if (t < 256)       cval = FQ[(((size_t)(t >> 6))*NB + b)*ND2 + (t & 63)];
    else if (t < 512)  cval = BFC[t - 256];
    else if (t < 768)  cval = BVC[t - 512];
    // ---- head-invariant per-row data (mask penalty + cosine terms) ----
    float mkv[4], c0v[4], c1v[4];
    {
        int rbase = w*16 + quad*4;
        for (int rg = 0; rg < 4; ++rg) {
            int r = rbase + rg;
            if (r < NL) {
                mkv[rg] = 1e9f * (1.0f - (float)mask[bL + r]);
                c0v[rg] = mmc[bL + r];
                c1v[rg] = mmc[NB*NL + bL + r];
            } else { mkv[rg] = 0.f; c0v[rg] = 0.f; c1v[rg] = 0.f; }
        }
    }

    // ---- A fragments: this warp's 16 fact rows, hi/lo bf16 (heavy VALU;
    //      hides the latency of the DMA + loads issued above) ----
    short8 afh[4], afl[4];
    const short8 zero8 = {0,0,0,0,0,0,0,0};
    {
        int row = w*16 + a15;
        for (int kk = 0; kk < 4; ++kk) {
            short8 vh = zero8, vl = zero8;
            if (row < NL) {
                const float* p = fact + ((size_t)(bL + row))*NDF + kk*32 + quad*8;
                float4 x0 = *(const float4*)p;
                float4 x1 = *(const float4*)(p + 4);
                float v[8] = {x0.x, x0.y, x0.z, x0.w, x1.x, x1.y, x1.z, x1.w};
                for (int j = 0; j < 8; ++j) {
                    short hs = f2bf(v[j]);
                    vh[j] = hs;
                    vl[j] = f2bf(v[j] - bf2f(hs));
                }
            }
            afh[kk] = vh;
            afl[kk] = vl;
        }
    }

    if (t < 256)       ((float*)fqS)[t]        = cval;
    else if (t < 512)  ((float*)bfcS)[t - 256] = cval;
    else if (t < 768)  ((float*)bvcS)[t - 512] = cval;
    __syncthreads();                            // drains DMA (vmcnt) + LDS writes

    const f32x4 zf = {0.f, 0.f, 0.f, 0.f};

    for (int h = 0; h < NH; ++h) {
        // ---- issue next-head DMA first (latency hides under compute) ----
        if (h + 1 < NH) {
            const char* hb = (const char*)WIMG + (size_t)(h+1)*HIMG;
            char* lb = (char*)&wS[(h+1) & 1][0];
            #pragma unroll
            for (int j = 0; j < 4; ++j)
                if (cOk[j]) GLOAD_LDS16(hb + srcOff[j], lb + ldsByte[j]);
        }
        // ---- merge of previous head by one dedicated warp (9..11) ----
        if (h > 0 && w == 8 + h) {
            const int ps = (h - 1) & 1;
            float M = pS[ps][0][0];
            for (int ww = 1; ww < NW; ++ww) M = fmaxf(M, pS[ps][ww][0]);
            float den = 0.f, num = 0.f, s1 = 0.f;
            for (int ww = 0; ww < NW; ++ww) {
                float e = __expf(pS[ps][ww][0] - M);
                den += e * pS[ps][ww][1];
                num += e * pS[ps][ww][2 + lane];
                s1  += pS[ps][ww][66 + lane];
            }
            out[(size_t)b*(NH*ND2) + (h-1)*ND2 + lane] = num * __fdividef(1.f, den) + 1e-7f * s1;
        }

        const float rt1a = __fdividef(1.f, tau1[h]);
        const float rt1b = __fdividef(1.f, tau1[NH + h]);
        const float t20 = tau2[h];
        const float t21 = tau2[NH + h];
        const float t22 = tau2[2*NH + h];

        float fqv[4], bfcv[4];
        for (int nt = 0; nt < 4; ++nt) {
            fqv[nt]  = fqS[h][nt*16 + a15];
            bfcv[nt] = bfcS[h][nt*16 + a15];
        }

        const __hip_bfloat16* wb = &wS[h & 1][0];

        // ---- ff GEMM, 3 passes: f_hi*w_hi + f_hi*w_lo + f_lo*w_hi ----
        f32x4 acc[4];
        for (int nt = 0; nt < 4; ++nt) acc[nt] = zf;
        __builtin_amdgcn_s_setprio(1);
        for (int kk = 0; kk < 4; ++kk) {
            const int gk = ((kk*4 + qrot) & 15) << 3;   // swizzled granule (halfwords)
            short8 bh[4], bl[4];
            for (int nt = 0; nt < 4; ++nt) {
                const __hip_bfloat16* p = wb + (nt*16 + a15)*KP + gk;
                bh[nt] = *(const short8*)p;
                bl[nt] = *(const short8*)(p + ND2*KP);
            }
            for (int nt = 0; nt < 4; ++nt) {
                acc[nt] = __builtin_amdgcn_mfma_f32_16x16x32_bf16(afh[kk], bh[nt], acc[nt], 0, 0, 0);
                acc[nt] = __builtin_amdgcn_mfma_f32_16x16x32_bf16(afh[kk], bl[nt], acc[nt], 0, 0, 0);
                acc[nt] = __builtin_amdgcn_mfma_f32_16x16x32_bf16(afl[kk], bh[nt], acc[nt], 0, 0, 0);
            }
        }
        __builtin_amdgcn_s_setprio(0);

        // ---- epilogue: silu, dot with fq (DPP reduce -> row-dot in all 16
        //      lanes of each row group), mask + cosine bias -> logits ----
        float lg[4];
        for (int rg = 0; rg < 4; ++rg) {
            float l = -3.0e38f;
            float s = 0.f;
            for (int nt = 0; nt < 4; ++nt)
                s += fsilu(acc[nt][rg] + bfcv[nt]) * fqv[nt];
            s = red16_add(s);
            int r = w*16 + quad*4 + rg;
            if (r < NL) {
                float dv = s - mkv[rg];
                float bias = c0v[rg]*rt1a + c1v[rg]*rt1b;
                l = t20*dv + t21*bias + t22*dv*bias;
            }
            lg[rg] = l;
        }

        // ---- warp-local softmax over own 16 rows (permlane cross-row) ----
        float m = fmaxf(fmaxf(lg[0], lg[1]), fmaxf(lg[2], lg[3]));
        m = swap32_max(swap16_max(m));
        float sw = 0.f;
        for (int rg = 0; rg < 4; ++rg) {
            float p = __expf(lg[rg] - m);       // invalid rows underflow to 0
            lg[rg] = p;
            sw += p;
        }
        sw = swap32_add(swap16_add(sw));

        // ---- fv GEMM: single hi*hi pass (slot 2), reuse acc ----
        for (int nt = 0; nt < 4; ++nt) acc[nt] = zf;
        __builtin_amdgcn_s_setprio(1);
        for (int kk = 0; kk < 4; ++kk) {
            const int gk = ((kk*4 + qrot) & 15) << 3;
            short8 bv[4];
            for (int nt = 0; nt < 4; ++nt)
                bv[nt] = *(const short8*)(wb + (2*ND2 + nt*16 + a15)*KP + gk);
            for (int nt = 0; nt < 4; ++nt)
                acc[nt] = __builtin_amdgcn_mfma_f32_16x16x32_bf16(afh[kk], bv[nt], acc[nt], 0, 0, 0);
        }
        __builtin_amdgcn_s_setprio(0);

        // ---- AV: oE = sum p*silu(fv), oS = sum silu(fv) (for the +1e-7 term) ----
        float bvcv[4];
        for (int nt = 0; nt < 4; ++nt) bvcv[nt] = bvcS[h][nt*16 + a15];
        float oE[4] = {0.f,0.f,0.f,0.f}, oS[4] = {0.f,0.f,0.f,0.f};
        for (int rg = 0; rg < 4; ++rg) {
            float p = lg[rg];
            int r = w*16 + quad*4 + rg;
            float vm = (r < NL) ? 1.f : 0.f;
            for (int nt = 0; nt < 4; ++nt) {
                float sv = fsilu(acc[nt][rg] + bvcv[nt]);
                oE[nt] += p * sv;
                oS[nt] += vm * sv;
            }
        }
        for (int nt = 0; nt < 4; ++nt) {
            oE[nt] = swap32_add(swap16_add(oE[nt]));
            oS[nt] = swap32_add(swap16_add(oS[nt]));
        }
        if (lane == 0) { pS[h & 1][w][0] = m; pS[h & 1][w][1] = sw; }
        if (quad == 0)
            for (int nt = 0; nt < 4; ++nt) {
                pS[h & 1][w][2  + nt*16 + a15] = oE[nt];
                pS[h & 1][w][66 + nt*16 + a15] = oS[nt];
            }
        __syncthreads();                        // pS[h&1] ready; DMA for (h+1) drained
    }

    // ---- final merge (head 3) by warp 12 ----
    if (w == 12) {
        const int ps = (NH - 1) & 1;
        float M = pS[ps][0][0];
        for (int ww = 1; ww < NW; ++ww) M = fmaxf(M, pS[ps][ww][0]);
        float den = 0.f, num = 0.f, s1 = 0.f;
        for (int ww = 0; ww < NW; ++ww) {
            float e = __expf(pS[ps][ww][0] - M);
            den += e * pS[ps][ww][1];
            num += e * pS[ps][ww][2 + lane];
            s1  += pS[ps][ww][66 + lane];
        }
        out[(size_t)b*(NH*ND2) + (NH-1)*ND2 + lane] = num * __fdividef(1.f, den) + 1e-7f * s1;
    }
}

extern "C" void kernel_launch(void* const* d_in, const int* in_sizes, int n_in,
                              void* d_out, int out_size, void* d_ws, size_t ws_size,
                              hipStream_t stream) {
    const float* query = (const float*)d_in[0];
    const float* fact  = (const float*)d_in[1];
    const int*   maskp = (const int*)d_in[2];
    const float* mmc   = (const float*)d_in[3];
    const float* Wq1 = (const float*)d_in[4];
    const float* bq1 = (const float*)d_in[5];
    const float* Wq2 = (const float*)d_in[6];
    const float* bq2 = (const float*)d_in[7];
    const float* Wf1 = (const float*)d_in[8];
    const float* bf1 = (const float*)d_in[9];
    const float* Wf2 = (const float*)d_in[10];
    const float* bf2 = (const float*)d_in[11];
    const float* Wv1 = (const float*)d_in[12];
    const float* bv1 = (const float*)d_in[13];
    const float* Wv2 = (const float*)d_in[14];
    const float* bv2 = (const float*)d_in[15];
    const float* tau1 = (const float*)d_in[16];
    const float* tau2 = (const float*)d_in[17];

    char* ws = (char*)d_ws;
    float*          WQC  = (float*)(ws + OFF_WQC);
    float*          BQC  = (float*)(ws + OFF_BQC);
    float*          FQ   = (float*)(ws + OFF_FQ);
    __hip_bfloat16* WIMG = (__hip_bfloat16*)(ws + OFF_WIMG);
    float*          BFC  = (float*)(ws + OFF_BFC);
    float*          BVC  = (float*)(ws + OFF_BVC);

    k_combine<<<771, 256, 0, stream>>>(Wq1, bq1, Wq2, bq2, Wf1, bf1, Wf2, bf2,
                                       Wv1, bv1, Wv2, bv2, WQC, BQC, WIMG, BFC, BVC);
    k_fq<<<NB/2, 256, 0, stream>>>(query, WQC, BQC, FQ);
    k_main<<<NB, NT, 0, stream>>>(fact, maskp, mmc, tau1, tau2, FQ, BFC, BVC, WIMG,
                                  (float*)d_out);
}